// Round 9
// baseline (581.774 us; speedup 1.0000x reference)
//
#include <hip/hip_runtime.h>
#include <hip/hip_bf16.h>

#define DID 512              // in_dim (K)
#define NV  512              // n_vars (tokens per batch)
#define NB  64               // batch
#define OD  720              // out_dim
#define OPAD 768             // out_dim padded to 128-multiple
#define NE  8                // experts
#define NTOK (NB * NV)       // 32768 tokens
#define MAXTILE 512          // >= 28 + 32768/128 = 284 worst case

typedef short  bf16x8 __attribute__((ext_vector_type(8)));
typedef float  f32x4  __attribute__((ext_vector_type(4)));

// ---- workspace offsets (bytes) ----
#define XT_OFF    0u          // bf16 [B][V][D]          33,554,432
#define WB_OFF    33554432u   // bf16 [E][OPAD][D]        6,291,456
#define PID_OFF   39845888u   // int  [NTOK] pair id        131,072
#define C1D_OFF   39976960u   // f32  [NTOK] coef lo-e      131,072
#define C2D_OFF   40108032u   // f32  [NTOK] coef hi-e      131,072
#define TL_OFF    40239104u   // int  [NTOK] bucketed tok   131,072
#define CL1_OFF   40370176u   // f32  [NTOK]                131,072
#define CL2_OFF   40501248u   // f32  [NTOK]                131,072
#define BCNT_OFF  40632320u   // int[64]
#define BFILL_OFF 40632576u   // int[64]
#define BOFF_OFF  40632832u   // int[64]
#define TPID_OFF  40633088u   // int[MAXTILE]
#define TT0_OFF   40635136u   // int[MAXTILE]
#define TEND_OFF  40637184u   // int[MAXTILE]
#define NT_OFF    40639232u   // int[1]
#define SCR_OFF   40639488u   // bf16 [NTOK][OD]         47,185,920
#define SCR_END   87825408u

static __device__ __forceinline__ ushort f2bf(float f) {
  unsigned u = __float_as_uint(f);
  unsigned r = (u + 0x7fffu + ((u >> 16) & 1u)) >> 16;   // RNE
  return (ushort)r;
}
static __device__ __forceinline__ float bf2f(ushort u) {
  return __uint_as_float(((unsigned)u) << 16);
}
static __device__ __forceinline__ void async16(const ushort* g, ushort* l) {
  __builtin_amdgcn_global_load_lds((__attribute__((address_space(1))) void*)(g),
                                   (__attribute__((address_space(3))) void*)(l),
                                   16, 0, 0);
}
// chunk swizzle: spreads 64B-stride rows across 8 bank-sets (2-way = free)
static __device__ __forceinline__ int swz(int r) { return (r & 3) ^ ((r >> 2) & 1); }

// ---------------------------------------------------------------------------
// Fused: x [B][D][V] fp32 -> XT [B][V][D] bf16  AND  gating (fp32 exact).
// xt stores deferred in regs, burst-written (R7 win: full-line writebacks).
// ---------------------------------------------------------------------------
__global__ __launch_bounds__(512, 4) void k_gatet(const float* __restrict__ x,
                                                  const float* __restrict__ Wg,
                                                  ushort* __restrict__ xt,
                                                  int* __restrict__ pairid,
                                                  float* __restrict__ c1d,
                                                  float* __restrict__ c2d,
                                                  int* __restrict__ bcnt) {
  __shared__ float wg[NE * DID];          // 16 KB
  __shared__ float part[8][64][NE + 1];   // pad->stride 9: bank-conflict-free
  __shared__ int cnt64[64];
  const int tid = threadIdx.x;
  for (int i = tid; i < NE * DID / 4; i += 512)
    ((float4*)wg)[i] = ((const float4*)Wg)[i];
  if (tid < 64) cnt64[tid] = 0;
  __syncthreads();

  const int b    = blockIdx.y;
  const int v0   = blockIdx.x * 64;
  const int w    = tid >> 6;              // 8 waves, each owns 64 dims
  const int lane = tid & 63;
  const int v    = v0 + lane;
  const int d0   = w * 64;
  const float* xp = x + ((size_t)b * DID + d0) * NV + v;
  ushort* xtp = xt + ((size_t)b * NV + v) * DID + d0;

  float acc[NE];
#pragma unroll
  for (int e = 0; e < NE; ++e) acc[e] = 0.f;

  bf16x8 pk8[8];                          // this thread's 128B xt line
  for (int c = 0; c < 64; c += 8) {
    float xv[8];
#pragma unroll
    for (int u = 0; u < 8; ++u) xv[u] = xp[(size_t)(c + u) * NV];
#pragma unroll
    for (int e = 0; e < NE; ++e) {
      const float* wp = &wg[e * DID + d0 + c];
      float4 wa = *(const float4*)wp;
      float4 wb4 = *(const float4*)(wp + 4);
      acc[e] += xv[0] * wa.x + xv[1] * wa.y + xv[2] * wa.z + xv[3] * wa.w
              + xv[4] * wb4.x + xv[5] * wb4.y + xv[6] * wb4.z + xv[7] * wb4.w;
    }
    bf16x8 pk;
#pragma unroll
    for (int u = 0; u < 8; ++u) pk[u] = (short)f2bf(xv[u]);
    pk8[c >> 3] = pk;
  }
#pragma unroll
  for (int ci = 0; ci < 8; ++ci)
    *(bf16x8*)(xtp + ci * 8) = pk8[ci];

#pragma unroll
  for (int e = 0; e < NE; ++e) part[w][lane][e] = acc[e];
  __syncthreads();

  if (tid < 64) {
    float a[NE];
#pragma unroll
    for (int e = 0; e < NE; ++e) {
      float s = part[0][tid][e];
#pragma unroll
      for (int q = 1; q < 8; ++q) s += part[q][tid][e];
      a[e] = s;
    }
    float mx = a[0];
#pragma unroll
    for (int e = 1; e < NE; ++e) mx = fmaxf(mx, a[e]);
    float sum = 0.f;
#pragma unroll
    for (int e = 0; e < NE; ++e) { a[e] = __expf(a[e] - mx); sum += a[e]; }
    const float inv = 1.f / sum;

    int i1 = 0; float g1 = a[0];
#pragma unroll
    for (int e = 1; e < NE; ++e) if (a[e] > g1) { g1 = a[e]; i1 = e; }
    int i2 = -1; float g2 = -1.f;
#pragma unroll
    for (int e = 0; e < NE; ++e) if (e != i1 && a[e] > g2) { g2 = a[e]; i2 = e; }
    g1 *= inv; g2 *= inv;

    int ea, eb; float ca, cb;
    if (i1 < i2) { ea = i1; eb = i2; ca = g1; cb = g2; }
    else         { ea = i2; eb = i1; ca = g2; cb = g1; }
    const int pid = ea * 8 + eb;
    const int t = b * NV + v0 + tid;
    pairid[t] = pid; c1d[t] = ca; c2d[t] = cb;
    atomicAdd(&cnt64[pid], 1);
  }
  __syncthreads();
  if (tid < 64 && cnt64[tid]) atomicAdd(&bcnt[tid], cnt64[tid]);
}

// ---------------------------------------------------------------------------
// We [E][720][512] fp32 -> WB [E][768][512] bf16 (pad rows zero)
// ---------------------------------------------------------------------------
__global__ __launch_bounds__(256) void k_wbconv(const float* __restrict__ We,
                                                ushort* __restrict__ wb) {
  const int e = blockIdx.y;
  const int i = blockIdx.x * 256 + threadIdx.x;
  const int o = i >> 9;
  ushort val = 0;
  if (o < OD) val = f2bf(We[(size_t)e * OD * DID + i]);
  wb[(size_t)e * OPAD * DID + i] = val;
}

// ---------------------------------------------------------------------------
// Wave-parallel prefix over 64 buckets + tile table (1 wave, 2 shfl scans)
// ---------------------------------------------------------------------------
__global__ void k_prefix(const int* __restrict__ bcnt, int* __restrict__ boffs,
                         int* __restrict__ tpid, int* __restrict__ tt0,
                         int* __restrict__ tend, int* __restrict__ ntp) {
  const int p = threadIdx.x;            // 64 threads = 1 wave
  const int c = bcnt[p];
  int run = c;
#pragma unroll
  for (int s = 1; s < 64; s <<= 1) {
    int up = __shfl_up(run, s, 64);
    if (p >= s) run += up;
  }
  const int excl = run - c;             // exclusive token offset
  boffs[p] = excl;
  const int ntiles = (c + 127) >> 7;
  int trun = ntiles;
#pragma unroll
  for (int s = 1; s < 64; s <<= 1) {
    int up = __shfl_up(trun, s, 64);
    if (p >= s) trun += up;
  }
  const int texcl = trun - ntiles;      // exclusive tile offset
  for (int i = 0; i < ntiles; ++i) {
    tpid[texcl + i] = p;
    tt0[texcl + i]  = excl + i * 128;
    tend[texcl + i] = excl + c;
  }
  if (p == 63) ntp[0] = texcl + ntiles;
}

// ---------------------------------------------------------------------------
// Scatter tokens into packed per-bucket lists
// ---------------------------------------------------------------------------
__global__ __launch_bounds__(256) void k_scatter(const int* __restrict__ pairid,
                                                 const float* __restrict__ c1d,
                                                 const float* __restrict__ c2d,
                                                 const int* __restrict__ boffs,
                                                 int* __restrict__ bfill,
                                                 int* __restrict__ tlist,
                                                 float* __restrict__ cl1,
                                                 float* __restrict__ cl2) {
  __shared__ int cnt64[64], base64[64];
  const int tid = threadIdx.x;
  if (tid < 64) cnt64[tid] = 0;
  __syncthreads();
  const int t = blockIdx.x * 256 + tid;
  const int pid = pairid[t];
  const int p = atomicAdd(&cnt64[pid], 1);
  __syncthreads();
  if (tid < 64) base64[tid] = cnt64[tid] ? atomicAdd(&bfill[tid], cnt64[tid]) : 0;
  __syncthreads();
  const int slot = boffs[pid] + base64[pid] + p;
  tlist[slot] = t; cl1[slot] = c1d[t]; cl2[slot] = c2d[t];
}

// ---------------------------------------------------------------------------
// Pair-bucket GEMM, 128 tok x 256 o (R3 schedule), 2-buffer LDS rotation
// (48KB -> 3 blocks/CU): same two-barrier counted-vmcnt form, vmcnt 6 steady
// (stage kk done, kk+1 in flight), tail 6/0. Third resident block fills the
// barrier-convoy gaps the 2-block config exposed. Operands stay LDS-staged
// (R5/R8 proved direct global->VGPR operand loads lose to request amplif.).
// ---------------------------------------------------------------------------
__global__ __launch_bounds__(256, 3) void k_gemm(
    const ushort* __restrict__ xt, const ushort* __restrict__ wb,
    const float* __restrict__ be, const int* __restrict__ tlist,
    const float* __restrict__ cl1, const float* __restrict__ cl2,
    const int* __restrict__ tpid, const int* __restrict__ tt0,
    const int* __restrict__ tendarr, const int* __restrict__ ntp,
    ushort* __restrict__ scratch, float* __restrict__ out, int mode) {
  const int tile = blockIdx.x;
  if (tile >= ntp[0]) return;
  const int pid  = tpid[tile];
  const int t0   = tt0[tile];
  const int tend = tendarr[tile];
  const int e1 = pid >> 3, e2 = pid & 7;
  const int o0 = blockIdx.y * 256;

  __shared__ __align__(16) ushort As[2][8192];   // 2 x 16KB (256 o-rows x 32)
  __shared__ __align__(16) ushort Bs[2][4096];   // 2 x  8KB (128 tok-rows x 32)

  const int tid  = threadIdx.x;
  const int lane = tid & 63;
  const int w    = tid >> 6;

  // A staging: wave w covers linear slots [w*256,(w+1)*256) (4 instrs)
  int aoffA[4];
#pragma unroll
  for (int i = 0; i < 4; ++i) {
    const int f = w * 256 + i * 64 + lane;
    const int r = f >> 2, p = f & 3, q = p ^ swz(r);
    aoffA[i] = (o0 + r) * DID + q * 8;
  }
  // B staging: wave w covers slots [w*128,(w+1)*128) (2 instrs)
  int boffB[2];
#pragma unroll
  for (int i = 0; i < 2; ++i) {
    const int f = w * 128 + i * 64 + lane;
    const int r = f >> 2, p = f & 3, q = p ^ swz(r);
    const int sl = t0 + r;
    const int tk = (sl < tend) ? tlist[sl] : 0;
    boffB[i] = tk * DID + q * 8;
  }

  const int m    = lane & 15;
  const int quad = lane >> 4;
  const int wt   = (w & 1) * 64;      // token offset of this wave
  const int wo   = (w >> 1) * 128;    // o offset of this wave

  // ---- prologue preloads: keep loop VMEM = stage loads only ----
  float ratio[4], c2v[4]; int tokv[4]; bool gv[4];
#pragma unroll
  for (int j = 0; j < 4; ++j) {
    const int sl = t0 + wt + j * 16 + m;
    gv[j] = sl < tend;
    const float cc1 = gv[j] ? cl1[sl] : 0.f;
    const float cc2 = gv[j] ? cl2[sl] : 1.f;
    ratio[j] = cc1 / cc2;
    c2v[j]   = gv[j] ? cc2 : 0.f;
    tokv[j]  = gv[j] ? tlist[sl] : 0;
  }

  f32x4 acc[8][4];
#pragma unroll
  for (int i = 0; i < 8; ++i)
#pragma unroll
    for (int j = 0; j < 4; ++j) acc[i][j] = (f32x4){0.f, 0.f, 0.f, 0.f};

#define STAGE(t, buf) do {                                          \
    const int eA_ = ((t) < 16) ? e1 : e2;                           \
    const int k0_ = ((t) & 15) * 32;                                \
    const ushort* wA_ = wb + (size_t)eA_ * OPAD * DID + k0_;        \
    async16(wA_ + aoffA[0], &As[buf][w * 2048]);                    \
    async16(wA_ + aoffA[1], &As[buf][w * 2048 + 512]);              \
    async16(wA_ + aoffA[2], &As[buf][w * 2048 + 1024]);             \
    async16(wA_ + aoffA[3], &As[buf][w * 2048 + 1536]);             \
    async16(xt + boffB[0] + k0_, &Bs[buf][w * 1024]);               \
    async16(xt + boffB[1] + k0_, &Bs[buf][w * 1024 + 512]);         \
  } while (0)

#define FRAGS(buf)                                                       \
    bf16x8 af[8], bfr[4];                                                \
    {                                                                    \
      const ushort* Asb = &As[buf][0];                                   \
      const ushort* Bsb = &Bs[buf][0];                                   \
      _Pragma("unroll")                                                  \
      for (int i = 0; i < 8; ++i) {                                      \
        const int R = wo + i * 16 + m;                                   \
        af[i] = *(const bf16x8*)(Asb + R * 32 + ((quad ^ swz(R)) << 3)); \
      }                                                                  \
      _Pragma("unroll")                                                  \
      for (int j = 0; j < 4; ++j) {                                      \
        const int R = wt + j * 16 + m;                                   \
        bfr[j] = *(const bf16x8*)(Bsb + R * 32 + ((quad ^ swz(R)) << 3));\
      }                                                                  \
    }

#define MFMA32()                                                         \
    __builtin_amdgcn_s_setprio(1);                                       \
    _Pragma("unroll")                                                    \
    for (int i = 0; i < 8; ++i)                                          \
      _Pragma("unroll")                                                  \
      for (int j = 0; j < 4; ++j)                                        \
        acc[i][j] = __builtin_amdgcn_mfma_f32_16x16x32_bf16(af[i], bfr[j],\
                                                            acc[i][j], 0, 0, 0); \
    __builtin_amdgcn_s_setprio(0);

  // prologue: stages 0,1 in flight (12 VMEM ops/wave)
  STAGE(0, 0);
  STAGE(1, 1);

  int cur = 0;
  for (int kk = 0; kk < 30; ++kk) {
    asm volatile("s_waitcnt vmcnt(6)" ::: "memory");   // stage kk landed (mine)
    __builtin_amdgcn_s_barrier();                      // ... and everyone's

    if (kk == 16) {
      // fold expert-1: acc = (acc + be1[o]) * (c1/c2) per column
      const float* be1p = be + e1 * OD;
#pragma unroll
      for (int i = 0; i < 8; ++i) {
        const int ob = o0 + wo + i * 16 + quad * 4;
        float b0 = 0, b1 = 0, b2 = 0, b3 = 0;
        if (ob < OD) { b0 = be1p[ob]; b1 = be1p[ob + 1]; b2 = be1p[ob + 2]; b3 = be1p[ob + 3]; }
#pragma unroll
        for (int j = 0; j < 4; ++j) {
          acc[i][j][0] = (acc[i][j][0] + b0) * ratio[j];
          acc[i][j][1] = (acc[i][j][1] + b1) * ratio[j];
          acc[i][j][2] = (acc[i][j][2] + b2) * ratio[j];
          acc[i][j][3] = (acc[i][j][3] + b3) * ratio[j];
        }
      }
    }

    FRAGS(cur)
    asm volatile("s_waitcnt lgkmcnt(0)" ::: "memory"); // my reads of buf done
    __builtin_amdgcn_s_barrier();                      // everyone's reads done
    STAGE(kk + 2, cur);                                // overwrite just-read buf
    MFMA32()
    cur ^= 1;
  }

  // kk = 30 (buf 0): stage 31 outstanding -> wait 6
  {
    asm volatile("s_waitcnt vmcnt(6)" ::: "memory");
    __builtin_amdgcn_s_barrier();
    FRAGS(0)
    MFMA32()
  }
  // kk = 31 (buf 1): wait all
  {
    asm volatile("s_waitcnt vmcnt(0)" ::: "memory");
    __builtin_amdgcn_s_barrier();
    FRAGS(1)
    MFMA32()
  }

#undef STAGE
#undef FRAGS
#undef MFMA32

  // epilogue: val = c2 * (acc + be2[o]); write exactly once, no atomics
  const float* be2p = be + e2 * OD;
#pragma unroll
  for (int i = 0; i < 8; ++i) {
    const int ob = o0 + wo + i * 16 + quad * 4;
    if (ob < OD) {
      const float b0 = be2p[ob], b1 = be2p[ob + 1], b2 = be2p[ob + 2], b3 = be2p[ob + 3];
#pragma unroll
      for (int j = 0; j < 4; ++j) {
        if (gv[j]) {
          const float v0 = c2v[j] * (acc[i][j][0] + b0);
          const float v1 = c2v[j] * (acc[i][j][1] + b1);
          const float v2 = c2v[j] * (acc[i][j][2] + b2);
          const float v3 = c2v[j] * (acc[i][j][3] + b3);
          if (mode == 0) {
            ushort4 pk = make_ushort4(f2bf(v0), f2bf(v1), f2bf(v2), f2bf(v3));
            *(ushort4*)(scratch + (size_t)tokv[j] * OD + ob) = pk;
          } else {
            const int bb = tokv[j] >> 9, vv = tokv[j] & 511;
            float* op = out + ((size_t)bb * OD + ob) * NV + vv;
            op[0] = v0; op[(size_t)NV] = v1; op[2 * (size_t)NV] = v2; op[3 * (size_t)NV] = v3;
          }
        }
      }
    }
  }
}

// ---------------------------------------------------------------------------
// scratch bf16 [NTOK][OD] -> out fp32 [B][OD][V] (LDS transpose, coalesced)
// ---------------------------------------------------------------------------
__global__ __launch_bounds__(256) void k_combine(const ushort* __restrict__ scratch,
                                                 float* __restrict__ out) {
  __shared__ ushort s[64][68];   // 8B-aligned rows
  const int v0 = blockIdx.x * 64;
  const int o0 = blockIdx.y * 64;
  const int b  = blockIdx.z;
  const int tid = threadIdx.x;
#pragma unroll
  for (int it = 0; it < 2; ++it) {
    const int c = it * 256 + tid;            // 512 chunks of 8 o
    const int row = c >> 3, cg = c & 7;
    const int o = o0 + cg * 8;
    if (o + 8 <= OD) {
      const ushort* src = scratch + ((size_t)(b * NV + v0 + row)) * OD + o;
      ushort4 ua = *(const ushort4*)(src);
      ushort4 ub = *(const ushort4*)(src + 4);
      *(ushort4*)&s[row][cg * 8] = ua;
      *(ushort4*)&s[row][cg * 8 + 4] = ub;
    }
  }
  __syncthreads();
  const int vv = tid & 63;
  const int og = tid >> 6;                   // 4 groups of 8 o-pairs
#pragma unroll
  for (int oi = 0; oi < 8; ++oi) {
    const int ol = (og * 8 + oi) * 2;
    const int o = o0 + ol;
    if (o < OD) {
      ushort2 u = *(const ushort2*)&s[vv][ol];
      float* op = out + ((size_t)b * OD + o) * NV + v0 + vv;
      op[0]  = bf2f(u.x);
      op[NV] = bf2f(u.y);
    }
  }
}

// ---------------------------------------------------------------------------
extern "C" void kernel_launch(void* const* d_in, const int* in_sizes, int n_in,
                              void* d_out, int out_size, void* d_ws, size_t ws_size,
                              hipStream_t stream) {
  const float* x  = (const float*)d_in[0];
  const float* Wg = (const float*)d_in[1];
  const float* We = (const float*)d_in[2];
  const float* be = (const float*)d_in[3];
  float* out = (float*)d_out;

  char* ws = (char*)d_ws;
  ushort* xt     = (ushort*)(ws + XT_OFF);
  ushort* wb     = (ushort*)(ws + WB_OFF);
  int*    pairid = (int*)   (ws + PID_OFF);
  float*  c1d    = (float*) (ws + C1D_OFF);
  float*  c2d    = (float*) (ws + C2D_OFF);
  int*    tlist  = (int*)   (ws + TL_OFF);
  float*  cl1    = (float*) (ws + CL1_OFF);
  float*  cl2    = (float*) (ws + CL2_OFF);
  int*    bcnt   = (int*)   (ws + BCNT_OFF);
  int*    bfill  = (int*)   (ws + BFILL_OFF);
  int*    boffs  = (int*)   (ws + BOFF_OFF);
  int*    tpid   = (int*)   (ws + TPID_OFF);
  int*    tt0    = (int*)   (ws + TT0_OFF);
  int*    tend   = (int*)   (ws + TEND_OFF);
  int*    ntp    = (int*)   (ws + NT_OFF);
  ushort* scratch= (ushort*)(ws + SCR_OFF);

  const int mode = (ws_size >= (size_t)SCR_END) ? 0 : 1;  // constant across calls

  (void)hipMemsetAsync(bcnt, 0, 512, stream);             // bcnt + bfill

  k_gatet<<<dim3(NV / 64, NB), 512, 0, stream>>>(x, Wg, xt, pairid, c1d, c2d, bcnt);
  k_wbconv<<<dim3(OPAD * DID / 256, NE), 256, 0, stream>>>(We, wb);
  k_prefix<<<1, 64, 0, stream>>>(bcnt, boffs, tpid, tt0, tend, ntp);
  k_scatter<<<NTOK / 256, 256, 0, stream>>>(pairid, c1d, c2d, boffs, bfill,
                                            tlist, cl1, cl2);
  k_gemm<<<dim3(320, OPAD / 256), 256, 0, stream>>>(xt, wb, be, tlist, cl1, cl2,
                                                    tpid, tt0, tend, ntp,
                                                    scratch, out, mode);
  if (mode == 0)
    k_combine<<<dim3(NV / 64, (OD + 63) / 64, NB), 256, 0, stream>>>(scratch, out);
}

// Round 10
// 289.951 us; speedup vs baseline: 2.0065x; 2.0065x over previous
//
#include <hip/hip_runtime.h>
#include <hip/hip_bf16.h>

#define DID 512              // in_dim (K)
#define NV  512              // n_vars (tokens per batch)
#define NB  64               // batch
#define OD  720              // out_dim
#define OPAD 768             // out_dim padded to 128-multiple
#define NE  8                // experts
#define NTOK (NB * NV)       // 32768 tokens
#define MAXTILE 512          // >= 28 + 32768/128 = 284 worst case

typedef short  bf16x8 __attribute__((ext_vector_type(8)));
typedef float  f32x4  __attribute__((ext_vector_type(4)));

// ---- workspace offsets (bytes) ----
#define XT_OFF    0u          // bf16 [B][V][D]          33,554,432
#define WB_OFF    33554432u   // bf16 [E][OPAD][D]        6,291,456
#define PID_OFF   39845888u   // int  [NTOK] pair id        131,072
#define C1D_OFF   39976960u   // f32  [NTOK] coef lo-e      131,072
#define C2D_OFF   40108032u   // f32  [NTOK] coef hi-e      131,072
#define TL_OFF    40239104u   // int  [NTOK] bucketed tok   131,072
#define CL1_OFF   40370176u   // f32  [NTOK]                131,072
#define CL2_OFF   40501248u   // f32  [NTOK]                131,072
#define BCNT_OFF  40632320u   // int[64]
#define BFILL_OFF 40632576u   // int[64]
#define BOFF_OFF  40632832u   // int[64]
#define TPID_OFF  40633088u   // int[MAXTILE]
#define TT0_OFF   40635136u   // int[MAXTILE]
#define TEND_OFF  40637184u   // int[MAXTILE]
#define NT_OFF    40639232u   // int[1]
#define SCR_OFF   40639488u   // bf16 [NTOK][OD]         47,185,920
#define SCR_END   87825408u

static __device__ __forceinline__ ushort f2bf(float f) {
  unsigned u = __float_as_uint(f);
  unsigned r = (u + 0x7fffu + ((u >> 16) & 1u)) >> 16;   // RNE
  return (ushort)r;
}
static __device__ __forceinline__ float bf2f(ushort u) {
  return __uint_as_float(((unsigned)u) << 16);
}
static __device__ __forceinline__ void async16(const ushort* g, ushort* l) {
  __builtin_amdgcn_global_load_lds((__attribute__((address_space(1))) void*)(g),
                                   (__attribute__((address_space(3))) void*)(l),
                                   16, 0, 0);
}
// chunk swizzle: spreads 64B-stride rows across 8 bank-sets (2-way = free)
static __device__ __forceinline__ int swz(int r) { return (r & 3) ^ ((r >> 2) & 1); }

// ---------------------------------------------------------------------------
// Fused: x [B][D][V] fp32 -> XT [B][V][D] bf16  AND  gating (fp32 exact).
// xt stores deferred in regs, burst-written (R7 win: full-line writebacks).
// ---------------------------------------------------------------------------
__global__ __launch_bounds__(512, 4) void k_gatet(const float* __restrict__ x,
                                                  const float* __restrict__ Wg,
                                                  ushort* __restrict__ xt,
                                                  int* __restrict__ pairid,
                                                  float* __restrict__ c1d,
                                                  float* __restrict__ c2d,
                                                  int* __restrict__ bcnt) {
  __shared__ float wg[NE * DID];          // 16 KB
  __shared__ float part[8][64][NE + 1];   // pad->stride 9: bank-conflict-free
  __shared__ int cnt64[64];
  const int tid = threadIdx.x;
  for (int i = tid; i < NE * DID / 4; i += 512)
    ((float4*)wg)[i] = ((const float4*)Wg)[i];
  if (tid < 64) cnt64[tid] = 0;
  __syncthreads();

  const int b    = blockIdx.y;
  const int v0   = blockIdx.x * 64;
  const int w    = tid >> 6;              // 8 waves, each owns 64 dims
  const int lane = tid & 63;
  const int v    = v0 + lane;
  const int d0   = w * 64;
  const float* xp = x + ((size_t)b * DID + d0) * NV + v;
  ushort* xtp = xt + ((size_t)b * NV + v) * DID + d0;

  float acc[NE];
#pragma unroll
  for (int e = 0; e < NE; ++e) acc[e] = 0.f;

  bf16x8 pk8[8];                          // this thread's 128B xt line
  for (int c = 0; c < 64; c += 8) {
    float xv[8];
#pragma unroll
    for (int u = 0; u < 8; ++u) xv[u] = xp[(size_t)(c + u) * NV];
#pragma unroll
    for (int e = 0; e < NE; ++e) {
      const float* wp = &wg[e * DID + d0 + c];
      float4 wa = *(const float4*)wp;
      float4 wb4 = *(const float4*)(wp + 4);
      acc[e] += xv[0] * wa.x + xv[1] * wa.y + xv[2] * wa.z + xv[3] * wa.w
              + xv[4] * wb4.x + xv[5] * wb4.y + xv[6] * wb4.z + xv[7] * wb4.w;
    }
    bf16x8 pk;
#pragma unroll
    for (int u = 0; u < 8; ++u) pk[u] = (short)f2bf(xv[u]);
    pk8[c >> 3] = pk;
  }
#pragma unroll
  for (int ci = 0; ci < 8; ++ci)
    *(bf16x8*)(xtp + ci * 8) = pk8[ci];

#pragma unroll
  for (int e = 0; e < NE; ++e) part[w][lane][e] = acc[e];
  __syncthreads();

  if (tid < 64) {
    float a[NE];
#pragma unroll
    for (int e = 0; e < NE; ++e) {
      float s = part[0][tid][e];
#pragma unroll
      for (int q = 1; q < 8; ++q) s += part[q][tid][e];
      a[e] = s;
    }
    float mx = a[0];
#pragma unroll
    for (int e = 1; e < NE; ++e) mx = fmaxf(mx, a[e]);
    float sum = 0.f;
#pragma unroll
    for (int e = 0; e < NE; ++e) { a[e] = __expf(a[e] - mx); sum += a[e]; }
    const float inv = 1.f / sum;

    int i1 = 0; float g1 = a[0];
#pragma unroll
    for (int e = 1; e < NE; ++e) if (a[e] > g1) { g1 = a[e]; i1 = e; }
    int i2 = -1; float g2 = -1.f;
#pragma unroll
    for (int e = 0; e < NE; ++e) if (e != i1 && a[e] > g2) { g2 = a[e]; i2 = e; }
    g1 *= inv; g2 *= inv;

    int ea, eb; float ca, cb;
    if (i1 < i2) { ea = i1; eb = i2; ca = g1; cb = g2; }
    else         { ea = i2; eb = i1; ca = g2; cb = g1; }
    const int pid = ea * 8 + eb;
    const int t = b * NV + v0 + tid;
    pairid[t] = pid; c1d[t] = ca; c2d[t] = cb;
    atomicAdd(&cnt64[pid], 1);
  }
  __syncthreads();
  if (tid < 64 && cnt64[tid]) atomicAdd(&bcnt[tid], cnt64[tid]);
}

// ---------------------------------------------------------------------------
// We [E][720][512] fp32 -> WB [E][768][512] bf16 (pad rows zero)
// ---------------------------------------------------------------------------
__global__ __launch_bounds__(256) void k_wbconv(const float* __restrict__ We,
                                                ushort* __restrict__ wb) {
  const int e = blockIdx.y;
  const int i = blockIdx.x * 256 + threadIdx.x;
  const int o = i >> 9;
  ushort val = 0;
  if (o < OD) val = f2bf(We[(size_t)e * OD * DID + i]);
  wb[(size_t)e * OPAD * DID + i] = val;
}

// ---------------------------------------------------------------------------
// Wave-parallel prefix over 64 buckets + tile table (1 wave, 2 shfl scans)
// ---------------------------------------------------------------------------
__global__ void k_prefix(const int* __restrict__ bcnt, int* __restrict__ boffs,
                         int* __restrict__ tpid, int* __restrict__ tt0,
                         int* __restrict__ tend, int* __restrict__ ntp) {
  const int p = threadIdx.x;            // 64 threads = 1 wave
  const int c = bcnt[p];
  int run = c;
#pragma unroll
  for (int s = 1; s < 64; s <<= 1) {
    int up = __shfl_up(run, s, 64);
    if (p >= s) run += up;
  }
  const int excl = run - c;             // exclusive token offset
  boffs[p] = excl;
  const int ntiles = (c + 127) >> 7;
  int trun = ntiles;
#pragma unroll
  for (int s = 1; s < 64; s <<= 1) {
    int up = __shfl_up(trun, s, 64);
    if (p >= s) trun += up;
  }
  const int texcl = trun - ntiles;      // exclusive tile offset
  for (int i = 0; i < ntiles; ++i) {
    tpid[texcl + i] = p;
    tt0[texcl + i]  = excl + i * 128;
    tend[texcl + i] = excl + c;
  }
  if (p == 63) ntp[0] = texcl + ntiles;
}

// ---------------------------------------------------------------------------
// Scatter tokens into packed per-bucket lists
// ---------------------------------------------------------------------------
__global__ __launch_bounds__(256) void k_scatter(const int* __restrict__ pairid,
                                                 const float* __restrict__ c1d,
                                                 const float* __restrict__ c2d,
                                                 const int* __restrict__ boffs,
                                                 int* __restrict__ bfill,
                                                 int* __restrict__ tlist,
                                                 float* __restrict__ cl1,
                                                 float* __restrict__ cl2) {
  __shared__ int cnt64[64], base64[64];
  const int tid = threadIdx.x;
  if (tid < 64) cnt64[tid] = 0;
  __syncthreads();
  const int t = blockIdx.x * 256 + tid;
  const int pid = pairid[t];
  const int p = atomicAdd(&cnt64[pid], 1);
  __syncthreads();
  if (tid < 64) base64[tid] = cnt64[tid] ? atomicAdd(&bfill[tid], cnt64[tid]) : 0;
  __syncthreads();
  const int slot = boffs[pid] + base64[pid] + p;
  tlist[slot] = t; cl1[slot] = c1d[t]; cl2[slot] = c2d[t];
}

// ---------------------------------------------------------------------------
// Pair-bucket GEMM, 128 tok x 256 o block tile (R3/R7 schedule, measured
// 92.7us): 4 waves, acc 8x4 frags, 3-buffer counted-vmcnt rotation (vmcnt 12
// steady, tail 12/6/0), setprio around MFMA, fold trick at kk==16.
// NEW: XCD-locality block remap. Grid is linear 960 = 8 XCDs x 120; hardware
// round-robins block b to XCD b%8, so logical = (b&7)*120 + (b>>3) makes each
// tile's 3 o-blocks CONSECUTIVE ON ONE XCD -> the 128KB B token-panel is
// fetched from HBM once and L2-hit twice (R7 FETCH showed 3x refetch).
// Pure bijective permutation; correctness unaffected.
// ---------------------------------------------------------------------------
__global__ __launch_bounds__(256, 2) void k_gemm(
    const ushort* __restrict__ xt, const ushort* __restrict__ wb,
    const float* __restrict__ be, const int* __restrict__ tlist,
    const float* __restrict__ cl1, const float* __restrict__ cl2,
    const int* __restrict__ tpid, const int* __restrict__ tt0,
    const int* __restrict__ tendarr, const int* __restrict__ ntp,
    ushort* __restrict__ scratch, float* __restrict__ out, int mode) {
  const int bidx = blockIdx.x;
  const int logical = (bidx & 7) * 120 + (bidx >> 3);   // XCD-chunked remap
  const int tile = logical / 3;
  if (tile >= ntp[0]) return;
  const int pid  = tpid[tile];
  const int t0   = tt0[tile];
  const int tend = tendarr[tile];
  const int e1 = pid >> 3, e2 = pid & 7;
  const int o0 = (logical % 3) * 256;

  __shared__ __align__(16) ushort As[3][8192];   // 3 x 16KB (256 o-rows x 32)
  __shared__ __align__(16) ushort Bs[3][4096];   // 3 x  8KB (128 tok-rows x 32)

  const int tid  = threadIdx.x;
  const int lane = tid & 63;
  const int w    = tid >> 6;

  // A staging: wave w covers linear slots [w*256,(w+1)*256) (4 instrs)
  int aoffA[4];
#pragma unroll
  for (int i = 0; i < 4; ++i) {
    const int f = w * 256 + i * 64 + lane;
    const int r = f >> 2, p = f & 3, q = p ^ swz(r);
    aoffA[i] = (o0 + r) * DID + q * 8;
  }
  // B staging: wave w covers slots [w*128,(w+1)*128) (2 instrs)
  int boffB[2];
#pragma unroll
  for (int i = 0; i < 2; ++i) {
    const int f = w * 128 + i * 64 + lane;
    const int r = f >> 2, p = f & 3, q = p ^ swz(r);
    const int sl = t0 + r;
    const int tk = (sl < tend) ? tlist[sl] : 0;
    boffB[i] = tk * DID + q * 8;
  }

  const int m    = lane & 15;
  const int quad = lane >> 4;
  const int wt   = (w & 1) * 64;      // token offset of this wave
  const int wo   = (w >> 1) * 128;    // o offset of this wave

  // ---- prologue preloads: keep loop VMEM = stage loads only ----
  float ratio[4], c2v[4]; int tokv[4]; bool gv[4];
#pragma unroll
  for (int j = 0; j < 4; ++j) {
    const int sl = t0 + wt + j * 16 + m;
    gv[j] = sl < tend;
    const float cc1 = gv[j] ? cl1[sl] : 0.f;
    const float cc2 = gv[j] ? cl2[sl] : 1.f;
    ratio[j] = cc1 / cc2;
    c2v[j]   = gv[j] ? cc2 : 0.f;
    tokv[j]  = gv[j] ? tlist[sl] : 0;
  }

  f32x4 acc[8][4];
#pragma unroll
  for (int i = 0; i < 8; ++i)
#pragma unroll
    for (int j = 0; j < 4; ++j) acc[i][j] = (f32x4){0.f, 0.f, 0.f, 0.f};

#define STAGE(t, buf) do {                                          \
    const int eA_ = ((t) < 16) ? e1 : e2;                           \
    const int k0_ = ((t) & 15) * 32;                                \
    const ushort* wA_ = wb + (size_t)eA_ * OPAD * DID + k0_;        \
    async16(wA_ + aoffA[0], &As[buf][w * 2048]);                    \
    async16(wA_ + aoffA[1], &As[buf][w * 2048 + 512]);              \
    async16(wA_ + aoffA[2], &As[buf][w * 2048 + 1024]);             \
    async16(wA_ + aoffA[3], &As[buf][w * 2048 + 1536]);             \
    async16(xt + boffB[0] + k0_, &Bs[buf][w * 1024]);               \
    async16(xt + boffB[1] + k0_, &Bs[buf][w * 1024 + 512]);         \
  } while (0)

#define FRAGS(buf)                                                       \
    bf16x8 af[8], bfr[4];                                                \
    {                                                                    \
      const ushort* Asb = &As[buf][0];                                   \
      const ushort* Bsb = &Bs[buf][0];                                   \
      _Pragma("unroll")                                                  \
      for (int i = 0; i < 8; ++i) {                                      \
        const int R = wo + i * 16 + m;                                   \
        af[i] = *(const bf16x8*)(Asb + R * 32 + ((quad ^ swz(R)) << 3)); \
      }                                                                  \
      _Pragma("unroll")                                                  \
      for (int j = 0; j < 4; ++j) {                                      \
        const int R = wt + j * 16 + m;                                   \
        bfr[j] = *(const bf16x8*)(Bsb + R * 32 + ((quad ^ swz(R)) << 3));\
      }                                                                  \
    }

#define MFMA32()                                                         \
    __builtin_amdgcn_s_setprio(1);                                       \
    _Pragma("unroll")                                                    \
    for (int i = 0; i < 8; ++i)                                          \
      _Pragma("unroll")                                                  \
      for (int j = 0; j < 4; ++j)                                        \
        acc[i][j] = __builtin_amdgcn_mfma_f32_16x16x32_bf16(af[i], bfr[j],\
                                                            acc[i][j], 0, 0, 0); \
    __builtin_amdgcn_s_setprio(0);

  // prologue: stages 0,1,2 in flight (18 VMEM ops/wave)
  STAGE(0, 0);
  STAGE(1, 1);
  STAGE(2, 2);

  int cur = 0;
  for (int kk = 0; kk < 29; ++kk) {
    asm volatile("s_waitcnt vmcnt(12)" ::: "memory");  // stage kk landed (mine)
    __builtin_amdgcn_s_barrier();                      // ... and everyone's

    if (kk == 16) {
      // fold expert-1: acc = (acc + be1[o]) * (c1/c2) per column
      const float* be1p = be + e1 * OD;
#pragma unroll
      for (int i = 0; i < 8; ++i) {
        const int ob = o0 + wo + i * 16 + quad * 4;
        float b0 = 0, b1 = 0, b2 = 0, b3 = 0;
        if (ob < OD) { b0 = be1p[ob]; b1 = be1p[ob + 1]; b2 = be1p[ob + 2]; b3 = be1p[ob + 3]; }
#pragma unroll
        for (int j = 0; j < 4; ++j) {
          acc[i][j][0] = (acc[i][j][0] + b0) * ratio[j];
          acc[i][j][1] = (acc[i][j][1] + b1) * ratio[j];
          acc[i][j][2] = (acc[i][j][2] + b2) * ratio[j];
          acc[i][j][3] = (acc[i][j][3] + b3) * ratio[j];
        }
      }
    }

    FRAGS(cur)
    asm volatile("s_waitcnt lgkmcnt(0)" ::: "memory"); // my reads of buf done
    __builtin_amdgcn_s_barrier();                      // everyone's reads done
    STAGE(kk + 3, cur);                                // safe to overwrite
    MFMA32()
    cur = (cur == 2) ? 0 : cur + 1;
  }

  // kk = 29 (buf 2): stages 29,30,31 outstanding -> wait 12
  {
    asm volatile("s_waitcnt vmcnt(12)" ::: "memory");
    __builtin_amdgcn_s_barrier();
    FRAGS(2)
    MFMA32()
  }
  // kk = 30 (buf 0): stages 30,31 outstanding -> wait 6
  {
    asm volatile("s_waitcnt vmcnt(6)" ::: "memory");
    __builtin_amdgcn_s_barrier();
    FRAGS(0)
    MFMA32()
  }
  // kk = 31 (buf 1): stage 31 outstanding -> wait 0
  {
    asm volatile("s_waitcnt vmcnt(0)" ::: "memory");
    __builtin_amdgcn_s_barrier();
    FRAGS(1)
    MFMA32()
  }

#undef STAGE
#undef FRAGS
#undef MFMA32

  // epilogue: val = c2 * (acc + be2[o]); write exactly once, no atomics
  const float* be2p = be + e2 * OD;
#pragma unroll
  for (int i = 0; i < 8; ++i) {
    const int ob = o0 + wo + i * 16 + quad * 4;
    if (ob < OD) {
      const float b0 = be2p[ob], b1 = be2p[ob + 1], b2 = be2p[ob + 2], b3 = be2p[ob + 3];
#pragma unroll
      for (int j = 0; j < 4; ++j) {
        if (gv[j]) {
          const float v0 = c2v[j] * (acc[i][j][0] + b0);
          const float v1 = c2v[j] * (acc[i][j][1] + b1);
          const float v2 = c2v[j] * (acc[i][j][2] + b2);
          const float v3 = c2v[j] * (acc[i][j][3] + b3);
          if (mode == 0) {
            ushort4 pk = make_ushort4(f2bf(v0), f2bf(v1), f2bf(v2), f2bf(v3));
            *(ushort4*)(scratch + (size_t)tokv[j] * OD + ob) = pk;
          } else {
            const int bb = tokv[j] >> 9, vv = tokv[j] & 511;
            float* op = out + ((size_t)bb * OD + ob) * NV + vv;
            op[0] = v0; op[(size_t)NV] = v1; op[2 * (size_t)NV] = v2; op[3 * (size_t)NV] = v3;
          }
        }
      }
    }
  }
}

// ---------------------------------------------------------------------------
// scratch bf16 [NTOK][OD] -> out fp32 [B][OD][V] (LDS transpose, coalesced)
// ---------------------------------------------------------------------------
__global__ __launch_bounds__(256) void k_combine(const ushort* __restrict__ scratch,
                                                 float* __restrict__ out) {
  __shared__ ushort s[64][68];   // 8B-aligned rows
  const int v0 = blockIdx.x * 64;
  const int o0 = blockIdx.y * 64;
  const int b  = blockIdx.z;
  const int tid = threadIdx.x;
#pragma unroll
  for (int it = 0; it < 2; ++it) {
    const int c = it * 256 + tid;            // 512 chunks of 8 o
    const int row = c >> 3, cg = c & 7;
    const int o = o0 + cg * 8;
    if (o + 8 <= OD) {
      const ushort* src = scratch + ((size_t)(b * NV + v0 + row)) * OD + o;
      ushort4 ua = *(const ushort4*)(src);
      ushort4 ub = *(const ushort4*)(src + 4);
      *(ushort4*)&s[row][cg * 8] = ua;
      *(ushort4*)&s[row][cg * 8 + 4] = ub;
    }
  }
  __syncthreads();
  const int vv = tid & 63;
  const int og = tid >> 6;                   // 4 groups of 8 o-pairs
#pragma unroll
  for (int oi = 0; oi < 8; ++oi) {
    const int ol = (og * 8 + oi) * 2;
    const int o = o0 + ol;
    if (o < OD) {
      ushort2 u = *(const ushort2*)&s[vv][ol];
      float* op = out + ((size_t)b * OD + o) * NV + v0 + vv;
      op[0]  = bf2f(u.x);
      op[NV] = bf2f(u.y);
    }
  }
}

// ---------------------------------------------------------------------------
extern "C" void kernel_launch(void* const* d_in, const int* in_sizes, int n_in,
                              void* d_out, int out_size, void* d_ws, size_t ws_size,
                              hipStream_t stream) {
  const float* x  = (const float*)d_in[0];
  const float* Wg = (const float*)d_in[1];
  const float* We = (const float*)d_in[2];
  const float* be = (const float*)d_in[3];
  float* out = (float*)d_out;

  char* ws = (char*)d_ws;
  ushort* xt     = (ushort*)(ws + XT_OFF);
  ushort* wb     = (ushort*)(ws + WB_OFF);
  int*    pairid = (int*)   (ws + PID_OFF);
  float*  c1d    = (float*) (ws + C1D_OFF);
  float*  c2d    = (float*) (ws + C2D_OFF);
  int*    tlist  = (int*)   (ws + TL_OFF);
  float*  cl1    = (float*) (ws + CL1_OFF);
  float*  cl2    = (float*) (ws + CL2_OFF);
  int*    bcnt   = (int*)   (ws + BCNT_OFF);
  int*    bfill  = (int*)   (ws + BFILL_OFF);
  int*    boffs  = (int*)   (ws + BOFF_OFF);
  int*    tpid   = (int*)   (ws + TPID_OFF);
  int*    tt0    = (int*)   (ws + TT0_OFF);
  int*    tend   = (int*)   (ws + TEND_OFF);
  int*    ntp    = (int*)   (ws + NT_OFF);
  ushort* scratch= (ushort*)(ws + SCR_OFF);

  const int mode = (ws_size >= (size_t)SCR_END) ? 0 : 1;  // constant across calls

  (void)hipMemsetAsync(bcnt, 0, 512, stream);             // bcnt + bfill

  k_gatet<<<dim3(NV / 64, NB), 512, 0, stream>>>(x, Wg, xt, pairid, c1d, c2d, bcnt);
  k_wbconv<<<dim3(OPAD * DID / 256, NE), 256, 0, stream>>>(We, wb);
  k_prefix<<<1, 64, 0, stream>>>(bcnt, boffs, tpid, tt0, tend, ntp);
  k_scatter<<<NTOK / 256, 256, 0, stream>>>(pairid, c1d, c2d, boffs, bfill,
                                            tlist, cl1, cl2);
  k_gemm<<<dim3(960), 256, 0, stream>>>(xt, wb, be, tlist, cl1, cl2,
                                        tpid, tt0, tend, ntp,
                                        scratch, out, mode);
  if (mode == 0)
    k_combine<<<dim3(NV / 64, (OD + 63) / 64, NB), 256, 0, stream>>>(scratch, out);
}

// Round 11
// 287.667 us; speedup vs baseline: 2.0224x; 1.0079x over previous
//
#include <hip/hip_runtime.h>
#include <hip/hip_bf16.h>

#define DID 512              // in_dim (K)
#define NV  512              // n_vars (tokens per batch)
#define NB  64               // batch
#define OD  720              // out_dim
#define OPAD 768             // out_dim padded to 128-multiple
#define NE  8                // experts
#define NTOK (NB * NV)       // 32768 tokens
#define MAXTILE 512          // >= 28 + 32768/128 = 284 worst case

typedef short  bf16x8 __attribute__((ext_vector_type(8)));
typedef float  f32x4  __attribute__((ext_vector_type(4)));

// ---- workspace offsets (bytes) ----
#define XT_OFF    0u          // bf16 [B][V][D]          33,554,432
#define WB_OFF    33554432u   // bf16 [E][OPAD][D]        6,291,456
#define PID_OFF   39845888u   // int  [NTOK] pair id        131,072
#define C1D_OFF   39976960u   // f32  [NTOK] coef lo-e      131,072
#define C2D_OFF   40108032u   // f32  [NTOK] coef hi-e      131,072
#define TL_OFF    40239104u   // int  [NTOK] bucketed tok   131,072
#define CL1_OFF   40370176u   // f32  [NTOK]                131,072
#define CL2_OFF   40501248u   // f32  [NTOK]                131,072
#define BCNT_OFF  40632320u   // int[64]
#define BFILL_OFF 40632576u   // int[64]
#define BOFF_OFF  40632832u   // int[64]
#define TPID_OFF  40633088u   // int[MAXTILE]
#define TT0_OFF   40635136u   // int[MAXTILE]
#define TEND_OFF  40637184u   // int[MAXTILE]
#define NT_OFF    40639232u   // int[1]
#define SCR_OFF   40639488u   // bf16 [NTOK][OD]         47,185,920
#define SCR_END   87825408u

static __device__ __forceinline__ ushort f2bf(float f) {
  unsigned u = __float_as_uint(f);
  unsigned r = (u + 0x7fffu + ((u >> 16) & 1u)) >> 16;   // RNE
  return (ushort)r;
}
static __device__ __forceinline__ float bf2f(ushort u) {
  return __uint_as_float(((unsigned)u) << 16);
}
static __device__ __forceinline__ void async16(const ushort* g, ushort* l) {
  __builtin_amdgcn_global_load_lds((__attribute__((address_space(1))) void*)(g),
                                   (__attribute__((address_space(3))) void*)(l),
                                   16, 0, 0);
}
// chunk swizzle: spreads 64B-stride rows across 8 bank-sets (2-way = free)
static __device__ __forceinline__ int swz(int r) { return (r & 3) ^ ((r >> 2) & 1); }

// ---------------------------------------------------------------------------
// Fused: x [B][D][V] fp32 -> XT [B][V][D] bf16  AND  gating (fp32 exact).
// xt stores deferred in regs, burst-written (R7 win: full-line writebacks).
// ---------------------------------------------------------------------------
__global__ __launch_bounds__(512, 4) void k_gatet(const float* __restrict__ x,
                                                  const float* __restrict__ Wg,
                                                  ushort* __restrict__ xt,
                                                  int* __restrict__ pairid,
                                                  float* __restrict__ c1d,
                                                  float* __restrict__ c2d,
                                                  int* __restrict__ bcnt) {
  __shared__ float wg[NE * DID];          // 16 KB
  __shared__ float part[8][64][NE + 1];   // pad->stride 9: bank-conflict-free
  __shared__ int cnt64[64];
  const int tid = threadIdx.x;
  for (int i = tid; i < NE * DID / 4; i += 512)
    ((float4*)wg)[i] = ((const float4*)Wg)[i];
  if (tid < 64) cnt64[tid] = 0;
  __syncthreads();

  const int b    = blockIdx.y;
  const int v0   = blockIdx.x * 64;
  const int w    = tid >> 6;              // 8 waves, each owns 64 dims
  const int lane = tid & 63;
  const int v    = v0 + lane;
  const int d0   = w * 64;
  const float* xp = x + ((size_t)b * DID + d0) * NV + v;
  ushort* xtp = xt + ((size_t)b * NV + v) * DID + d0;

  float acc[NE];
#pragma unroll
  for (int e = 0; e < NE; ++e) acc[e] = 0.f;

  bf16x8 pk8[8];                          // this thread's 128B xt line
  for (int c = 0; c < 64; c += 8) {
    float xv[8];
#pragma unroll
    for (int u = 0; u < 8; ++u) xv[u] = xp[(size_t)(c + u) * NV];
#pragma unroll
    for (int e = 0; e < NE; ++e) {
      const float* wp = &wg[e * DID + d0 + c];
      float4 wa = *(const float4*)wp;
      float4 wb4 = *(const float4*)(wp + 4);
      acc[e] += xv[0] * wa.x + xv[1] * wa.y + xv[2] * wa.z + xv[3] * wa.w
              + xv[4] * wb4.x + xv[5] * wb4.y + xv[6] * wb4.z + xv[7] * wb4.w;
    }
    bf16x8 pk;
#pragma unroll
    for (int u = 0; u < 8; ++u) pk[u] = (short)f2bf(xv[u]);
    pk8[c >> 3] = pk;
  }
#pragma unroll
  for (int ci = 0; ci < 8; ++ci)
    *(bf16x8*)(xtp + ci * 8) = pk8[ci];

#pragma unroll
  for (int e = 0; e < NE; ++e) part[w][lane][e] = acc[e];
  __syncthreads();

  if (tid < 64) {
    float a[NE];
#pragma unroll
    for (int e = 0; e < NE; ++e) {
      float s = part[0][tid][e];
#pragma unroll
      for (int q = 1; q < 8; ++q) s += part[q][tid][e];
      a[e] = s;
    }
    float mx = a[0];
#pragma unroll
    for (int e = 1; e < NE; ++e) mx = fmaxf(mx, a[e]);
    float sum = 0.f;
#pragma unroll
    for (int e = 0; e < NE; ++e) { a[e] = __expf(a[e] - mx); sum += a[e]; }
    const float inv = 1.f / sum;

    int i1 = 0; float g1 = a[0];
#pragma unroll
    for (int e = 1; e < NE; ++e) if (a[e] > g1) { g1 = a[e]; i1 = e; }
    int i2 = -1; float g2 = -1.f;
#pragma unroll
    for (int e = 0; e < NE; ++e) if (e != i1 && a[e] > g2) { g2 = a[e]; i2 = e; }
    g1 *= inv; g2 *= inv;

    int ea, eb; float ca, cb;
    if (i1 < i2) { ea = i1; eb = i2; ca = g1; cb = g2; }
    else         { ea = i2; eb = i1; ca = g2; cb = g1; }
    const int pid = ea * 8 + eb;
    const int t = b * NV + v0 + tid;
    pairid[t] = pid; c1d[t] = ca; c2d[t] = cb;
    atomicAdd(&cnt64[pid], 1);
  }
  __syncthreads();
  if (tid < 64 && cnt64[tid]) atomicAdd(&bcnt[tid], cnt64[tid]);
}

// ---------------------------------------------------------------------------
// We [E][720][512] fp32 -> WB [E][768][512] bf16 (pad rows zero), x8 vector
// (8 elems/thread never straddle an o-row: rows are 512-wide, i % 8 == 0).
// ---------------------------------------------------------------------------
__global__ __launch_bounds__(256) void k_wbconv(const float* __restrict__ We,
                                                ushort* __restrict__ wb) {
  const int e = blockIdx.y;
  const int i = (blockIdx.x * 256 + threadIdx.x) * 8;
  const int o = i >> 9;
  bf16x8 pk = {0, 0, 0, 0, 0, 0, 0, 0};
  if (o < OD) {
    const float* src = We + (size_t)e * OD * DID + i;
    float4 a = *(const float4*)src;
    float4 c = *(const float4*)(src + 4);
    pk[0] = (short)f2bf(a.x); pk[1] = (short)f2bf(a.y);
    pk[2] = (short)f2bf(a.z); pk[3] = (short)f2bf(a.w);
    pk[4] = (short)f2bf(c.x); pk[5] = (short)f2bf(c.y);
    pk[6] = (short)f2bf(c.z); pk[7] = (short)f2bf(c.w);
  }
  *(bf16x8*)(wb + (size_t)e * OPAD * DID + i) = pk;
}

// ---------------------------------------------------------------------------
// Wave-parallel prefix over 64 buckets + tile table (1 wave, 2 shfl scans)
// ---------------------------------------------------------------------------
__global__ void k_prefix(const int* __restrict__ bcnt, int* __restrict__ boffs,
                         int* __restrict__ tpid, int* __restrict__ tt0,
                         int* __restrict__ tend, int* __restrict__ ntp) {
  const int p = threadIdx.x;            // 64 threads = 1 wave
  const int c = bcnt[p];
  int run = c;
#pragma unroll
  for (int s = 1; s < 64; s <<= 1) {
    int up = __shfl_up(run, s, 64);
    if (p >= s) run += up;
  }
  const int excl = run - c;             // exclusive token offset
  boffs[p] = excl;
  const int ntiles = (c + 127) >> 7;
  int trun = ntiles;
#pragma unroll
  for (int s = 1; s < 64; s <<= 1) {
    int up = __shfl_up(trun, s, 64);
    if (p >= s) trun += up;
  }
  const int texcl = trun - ntiles;      // exclusive tile offset
  for (int i = 0; i < ntiles; ++i) {
    tpid[texcl + i] = p;
    tt0[texcl + i]  = excl + i * 128;
    tend[texcl + i] = excl + c;
  }
  if (p == 63) ntp[0] = texcl + ntiles;
}

// ---------------------------------------------------------------------------
// Scatter tokens into packed per-bucket lists
// ---------------------------------------------------------------------------
__global__ __launch_bounds__(256) void k_scatter(const int* __restrict__ pairid,
                                                 const float* __restrict__ c1d,
                                                 const float* __restrict__ c2d,
                                                 const int* __restrict__ boffs,
                                                 int* __restrict__ bfill,
                                                 int* __restrict__ tlist,
                                                 float* __restrict__ cl1,
                                                 float* __restrict__ cl2) {
  __shared__ int cnt64[64], base64[64];
  const int tid = threadIdx.x;
  if (tid < 64) cnt64[tid] = 0;
  __syncthreads();
  const int t = blockIdx.x * 256 + tid;
  const int pid = pairid[t];
  const int p = atomicAdd(&cnt64[pid], 1);
  __syncthreads();
  if (tid < 64) base64[tid] = cnt64[tid] ? atomicAdd(&bfill[tid], cnt64[tid]) : 0;
  __syncthreads();
  const int slot = boffs[pid] + base64[pid] + p;
  tlist[slot] = t; cl1[slot] = c1d[t]; cl2[slot] = c2d[t];
}

// ---------------------------------------------------------------------------
// Pair-bucket GEMM, 128 tok x 256 o block tile (R3/R7 schedule, measured
// 92.7us): 4 waves, acc 8x4 frags, 3-buffer counted-vmcnt rotation (vmcnt 12
// steady, tail 12/6/0), setprio around MFMA, fold trick at kk==16.
// Grid exact R7: dim3(320, 3). R10's XCD remap cut FETCH 2.3x but bought no
// time (prefetch already hides source latency) -> dropped.
// ---------------------------------------------------------------------------
__global__ __launch_bounds__(256, 2) void k_gemm(
    const ushort* __restrict__ xt, const ushort* __restrict__ wb,
    const float* __restrict__ be, const int* __restrict__ tlist,
    const float* __restrict__ cl1, const float* __restrict__ cl2,
    const int* __restrict__ tpid, const int* __restrict__ tt0,
    const int* __restrict__ tendarr, const int* __restrict__ ntp,
    ushort* __restrict__ scratch, float* __restrict__ out, int mode) {
  const int tile = blockIdx.x;
  if (tile >= ntp[0]) return;
  const int pid  = tpid[tile];
  const int t0   = tt0[tile];
  const int tend = tendarr[tile];
  const int e1 = pid >> 3, e2 = pid & 7;
  const int o0 = blockIdx.y * 256;

  __shared__ __align__(16) ushort As[3][8192];   // 3 x 16KB (256 o-rows x 32)
  __shared__ __align__(16) ushort Bs[3][4096];   // 3 x  8KB (128 tok-rows x 32)

  const int tid  = threadIdx.x;
  const int lane = tid & 63;
  const int w    = tid >> 6;

  // A staging: wave w covers linear slots [w*256,(w+1)*256) (4 instrs)
  int aoffA[4];
#pragma unroll
  for (int i = 0; i < 4; ++i) {
    const int f = w * 256 + i * 64 + lane;
    const int r = f >> 2, p = f & 3, q = p ^ swz(r);
    aoffA[i] = (o0 + r) * DID + q * 8;
  }
  // B staging: wave w covers slots [w*128,(w+1)*128) (2 instrs)
  int boffB[2];
#pragma unroll
  for (int i = 0; i < 2; ++i) {
    const int f = w * 128 + i * 64 + lane;
    const int r = f >> 2, p = f & 3, q = p ^ swz(r);
    const int sl = t0 + r;
    const int tk = (sl < tend) ? tlist[sl] : 0;
    boffB[i] = tk * DID + q * 8;
  }

  const int m    = lane & 15;
  const int quad = lane >> 4;
  const int wt   = (w & 1) * 64;      // token offset of this wave
  const int wo   = (w >> 1) * 128;    // o offset of this wave

  // ---- prologue preloads: keep loop VMEM = stage loads only ----
  float ratio[4], c2v[4]; int tokv[4]; bool gv[4];
#pragma unroll
  for (int j = 0; j < 4; ++j) {
    const int sl = t0 + wt + j * 16 + m;
    gv[j] = sl < tend;
    const float cc1 = gv[j] ? cl1[sl] : 0.f;
    const float cc2 = gv[j] ? cl2[sl] : 1.f;
    ratio[j] = cc1 / cc2;
    c2v[j]   = gv[j] ? cc2 : 0.f;
    tokv[j]  = gv[j] ? tlist[sl] : 0;
  }

  f32x4 acc[8][4];
#pragma unroll
  for (int i = 0; i < 8; ++i)
#pragma unroll
    for (int j = 0; j < 4; ++j) acc[i][j] = (f32x4){0.f, 0.f, 0.f, 0.f};

#define STAGE(t, buf) do {                                          \
    const int eA_ = ((t) < 16) ? e1 : e2;                           \
    const int k0_ = ((t) & 15) * 32;                                \
    const ushort* wA_ = wb + (size_t)eA_ * OPAD * DID + k0_;        \
    async16(wA_ + aoffA[0], &As[buf][w * 2048]);                    \
    async16(wA_ + aoffA[1], &As[buf][w * 2048 + 512]);              \
    async16(wA_ + aoffA[2], &As[buf][w * 2048 + 1024]);             \
    async16(wA_ + aoffA[3], &As[buf][w * 2048 + 1536]);             \
    async16(xt + boffB[0] + k0_, &Bs[buf][w * 1024]);               \
    async16(xt + boffB[1] + k0_, &Bs[buf][w * 1024 + 512]);         \
  } while (0)

#define FRAGS(buf)                                                       \
    bf16x8 af[8], bfr[4];                                                \
    {                                                                    \
      const ushort* Asb = &As[buf][0];                                   \
      const ushort* Bsb = &Bs[buf][0];                                   \
      _Pragma("unroll")                                                  \
      for (int i = 0; i < 8; ++i) {                                      \
        const int R = wo + i * 16 + m;                                   \
        af[i] = *(const bf16x8*)(Asb + R * 32 + ((quad ^ swz(R)) << 3)); \
      }                                                                  \
      _Pragma("unroll")                                                  \
      for (int j = 0; j < 4; ++j) {                                      \
        const int R = wt + j * 16 + m;                                   \
        bfr[j] = *(const bf16x8*)(Bsb + R * 32 + ((quad ^ swz(R)) << 3));\
      }                                                                    \
    }

#define MFMA32()                                                         \
    __builtin_amdgcn_s_setprio(1);                                       \
    _Pragma("unroll")                                                    \
    for (int i = 0; i < 8; ++i)                                          \
      _Pragma("unroll")                                                  \
      for (int j = 0; j < 4; ++j)                                        \
        acc[i][j] = __builtin_amdgcn_mfma_f32_16x16x32_bf16(af[i], bfr[j],\
                                                            acc[i][j], 0, 0, 0); \
    __builtin_amdgcn_s_setprio(0);

  // prologue: stages 0,1,2 in flight (18 VMEM ops/wave)
  STAGE(0, 0);
  STAGE(1, 1);
  STAGE(2, 2);

  int cur = 0;
  for (int kk = 0; kk < 29; ++kk) {
    asm volatile("s_waitcnt vmcnt(12)" ::: "memory");  // stage kk landed (mine)
    __builtin_amdgcn_s_barrier();                      // ... and everyone's

    if (kk == 16) {
      // fold expert-1: acc = (acc + be1[o]) * (c1/c2) per column
      const float* be1p = be + e1 * OD;
#pragma unroll
      for (int i = 0; i < 8; ++i) {
        const int ob = o0 + wo + i * 16 + quad * 4;
        float b0 = 0, b1 = 0, b2 = 0, b3 = 0;
        if (ob < OD) { b0 = be1p[ob]; b1 = be1p[ob + 1]; b2 = be1p[ob + 2]; b3 = be1p[ob + 3]; }
#pragma unroll
        for (int j = 0; j < 4; ++j) {
          acc[i][j][0] = (acc[i][j][0] + b0) * ratio[j];
          acc[i][j][1] = (acc[i][j][1] + b1) * ratio[j];
          acc[i][j][2] = (acc[i][j][2] + b2) * ratio[j];
          acc[i][j][3] = (acc[i][j][3] + b3) * ratio[j];
        }
      }
    }

    FRAGS(cur)
    asm volatile("s_waitcnt lgkmcnt(0)" ::: "memory"); // my reads of buf done
    __builtin_amdgcn_s_barrier();                      // everyone's reads done
    STAGE(kk + 3, cur);                                // safe to overwrite
    MFMA32()
    cur = (cur == 2) ? 0 : cur + 1;
  }

  // kk = 29 (buf 2): stages 29,30,31 outstanding -> wait 12
  {
    asm volatile("s_waitcnt vmcnt(12)" ::: "memory");
    __builtin_amdgcn_s_barrier();
    FRAGS(2)
    MFMA32()
  }
  // kk = 30 (buf 0): stages 30,31 outstanding -> wait 6
  {
    asm volatile("s_waitcnt vmcnt(6)" ::: "memory");
    __builtin_amdgcn_s_barrier();
    FRAGS(0)
    MFMA32()
  }
  // kk = 31 (buf 1): stage 31 outstanding -> wait 0
  {
    asm volatile("s_waitcnt vmcnt(0)" ::: "memory");
    __builtin_amdgcn_s_barrier();
    FRAGS(1)
    MFMA32()
  }

#undef STAGE
#undef FRAGS
#undef MFMA32

  // epilogue: val = c2 * (acc + be2[o]); write exactly once, no atomics
  const float* be2p = be + e2 * OD;
#pragma unroll
  for (int i = 0; i < 8; ++i) {
    const int ob = o0 + wo + i * 16 + quad * 4;
    if (ob < OD) {
      const float b0 = be2p[ob], b1 = be2p[ob + 1], b2 = be2p[ob + 2], b3 = be2p[ob + 3];
#pragma unroll
      for (int j = 0; j < 4; ++j) {
        if (gv[j]) {
          const float v0 = c2v[j] * (acc[i][j][0] + b0);
          const float v1 = c2v[j] * (acc[i][j][1] + b1);
          const float v2 = c2v[j] * (acc[i][j][2] + b2);
          const float v3 = c2v[j] * (acc[i][j][3] + b3);
          if (mode == 0) {
            ushort4 pk = make_ushort4(f2bf(v0), f2bf(v1), f2bf(v2), f2bf(v3));
            *(ushort4*)(scratch + (size_t)tokv[j] * OD + ob) = pk;
          } else {
            const int bb = tokv[j] >> 9, vv = tokv[j] & 511;
            float* op = out + ((size_t)bb * OD + ob) * NV + vv;
            op[0] = v0; op[(size_t)NV] = v1; op[2 * (size_t)NV] = v2; op[3 * (size_t)NV] = v3;
          }
        }
      }
    }
  }
}

// ---------------------------------------------------------------------------
// scratch bf16 [NTOK][OD] -> out fp32 [B][OD][V] (LDS transpose, coalesced).
// LDS row stride 66 ushorts (33 dwords, odd) -> read-phase banks (vv + c)
// mod 32: conflict-free (stride 68 was 4-way: 2vv aliasing). Writes to LDS
// as 4B ushort2 pieces (odd stride breaks 8B alignment on odd rows).
// ---------------------------------------------------------------------------
__global__ __launch_bounds__(256) void k_combine(const ushort* __restrict__ scratch,
                                                 float* __restrict__ out) {
  __shared__ ushort s[64][66];
  const int v0 = blockIdx.x * 64;
  const int o0 = blockIdx.y * 64;
  const int b  = blockIdx.z;
  const int tid = threadIdx.x;
#pragma unroll
  for (int it = 0; it < 2; ++it) {
    const int c = it * 256 + tid;            // 512 chunks of 8 o
    const int row = c >> 3, cg = c & 7;
    const int o = o0 + cg * 8;
    if (o + 8 <= OD) {
      const ushort* src = scratch + ((size_t)(b * NV + v0 + row)) * OD + o;
      bf16x8 ua = *(const bf16x8*)(src);     // 16B aligned: OD*2 and o*2 are
      ushort* dst = &s[row][cg * 8];         // 16-multiples
      *(ushort2*)(dst)     = make_ushort2((ushort)ua[0], (ushort)ua[1]);
      *(ushort2*)(dst + 2) = make_ushort2((ushort)ua[2], (ushort)ua[3]);
      *(ushort2*)(dst + 4) = make_ushort2((ushort)ua[4], (ushort)ua[5]);
      *(ushort2*)(dst + 6) = make_ushort2((ushort)ua[6], (ushort)ua[7]);
    }
  }
  __syncthreads();
  const int vv = tid & 63;
  const int og = tid >> 6;                   // 4 groups of 8 o-pairs
#pragma unroll
  for (int oi = 0; oi < 8; ++oi) {
    const int ol = (og * 8 + oi) * 2;
    const int o = o0 + ol;
    if (o < OD) {
      ushort2 u = *(const ushort2*)&s[vv][ol];
      float* op = out + ((size_t)b * OD + o) * NV + v0 + vv;
      op[0]  = bf2f(u.x);
      op[NV] = bf2f(u.y);
    }
  }
}

// ---------------------------------------------------------------------------
extern "C" void kernel_launch(void* const* d_in, const int* in_sizes, int n_in,
                              void* d_out, int out_size, void* d_ws, size_t ws_size,
                              hipStream_t stream) {
  const float* x  = (const float*)d_in[0];
  const float* Wg = (const float*)d_in[1];
  const float* We = (const float*)d_in[2];
  const float* be = (const float*)d_in[3];
  float* out = (float*)d_out;

  char* ws = (char*)d_ws;
  ushort* xt     = (ushort*)(ws + XT_OFF);
  ushort* wb     = (ushort*)(ws + WB_OFF);
  int*    pairid = (int*)   (ws + PID_OFF);
  float*  c1d    = (float*) (ws + C1D_OFF);
  float*  c2d    = (float*) (ws + C2D_OFF);
  int*    tlist  = (int*)   (ws + TL_OFF);
  float*  cl1    = (float*) (ws + CL1_OFF);
  float*  cl2    = (float*) (ws + CL2_OFF);
  int*    bcnt   = (int*)   (ws + BCNT_OFF);
  int*    bfill  = (int*)   (ws + BFILL_OFF);
  int*    boffs  = (int*)   (ws + BOFF_OFF);
  int*    tpid   = (int*)   (ws + TPID_OFF);
  int*    tt0    = (int*)   (ws + TT0_OFF);
  int*    tend   = (int*)   (ws + TEND_OFF);
  int*    ntp    = (int*)   (ws + NT_OFF);
  ushort* scratch= (ushort*)(ws + SCR_OFF);

  const int mode = (ws_size >= (size_t)SCR_END) ? 0 : 1;  // constant across calls

  (void)hipMemsetAsync(bcnt, 0, 512, stream);             // bcnt + bfill

  k_gatet<<<dim3(NV / 64, NB), 512, 0, stream>>>(x, Wg, xt, pairid, c1d, c2d, bcnt);
  k_wbconv<<<dim3(OPAD * DID / 2048, NE), 256, 0, stream>>>(We, wb);
  k_prefix<<<1, 64, 0, stream>>>(bcnt, boffs, tpid, tt0, tend, ntp);
  k_scatter<<<NTOK / 256, 256, 0, stream>>>(pairid, c1d, c2d, boffs, bfill,
                                            tlist, cl1, cl2);
  k_gemm<<<dim3(320, OPAD / 256), 256, 0, stream>>>(xt, wb, be, tlist, cl1, cl2,
                                                    tpid, tt0, tend, ntp,
                                                    scratch, out, mode);
  if (mode == 0)
    k_combine<<<dim3(NV / 64, (OD + 63) / 64, NB), 256, 0, stream>>>(scratch, out);
}